// Round 10
// baseline (202.446 us; speedup 1.0000x reference)
//
#include <hip/hip_runtime.h>

typedef __attribute__((ext_vector_type(8))) short short8;
typedef __attribute__((ext_vector_type(4))) float f32x4;

__device__ __forceinline__ unsigned short f2bf(float f) {
    unsigned u = __float_as_uint(f);
    u += 0x7FFF + ((u >> 16) & 1);          // round-to-nearest-even
    return (unsigned short)(u >> 16);
}

__device__ __forceinline__ float readlane_f(float v, int l) {
    return __int_as_float(__builtin_amdgcn_readlane(__float_as_int(v), l));
}

__device__ __forceinline__ float bflo(unsigned u) { return __uint_as_float(u << 16); }
__device__ __forceinline__ float bfhi(unsigned u) { return __uint_as_float(u & 0xFFFF0000u); }

// ---------------------------------------------------------------------------
// 1) Coarse histogram over bucket = dst>>8 (round-5 verified form).
// ---------------------------------------------------------------------------
#define CHB 2048
__global__ __launch_bounds__(256) void chist_kernel(
    const int* __restrict__ edst, int* __restrict__ ccounts, int E, int C)
{
    __shared__ int lh[CHB];
    const int t = threadIdx.x;
    for (int i = t; i < C; i += 256) lh[i] = 0;
    __syncthreads();
    const int base = blockIdx.x * 2048;
    const int end = min(base + 2048, E);
    for (int i = base + t; i < end; i += 256)
        atomicAdd(&lh[edst[i] >> 8], 1);
    __syncthreads();
    for (int i = t; i < C; i += 256)
        if (lh[i]) atomicAdd(&ccounts[i], lh[i]);
}

// ---------------------------------------------------------------------------
// 2) Single-block exclusive scan over C coarse counts -> cstarts + cursor.
// ---------------------------------------------------------------------------
__global__ __launch_bounds__(256) void cscan_kernel(
    const int* __restrict__ ccounts, int* __restrict__ cstarts,
    int* __restrict__ cursor, int C)
{
    __shared__ int sd[256];
    const int t = threadIdx.x;
    const int per = (C + 255) >> 8;        // items per thread (<=8 for C<=2048)
    int c[8]; int s = 0;
#pragma unroll
    for (int k = 0; k < 8; ++k) {
        const int idx = t * per + k;
        c[k] = (k < per && idx < C) ? ccounts[idx] : 0;
        s += c[k];
    }
    sd[t] = s; __syncthreads();
    for (int off = 1; off < 256; off <<= 1) {
        int x = (t >= off) ? sd[t - off] : 0;
        __syncthreads();
        sd[t] += x;
        __syncthreads();
    }
    int run = sd[t] - s;
#pragma unroll
    for (int k = 0; k < 8; ++k) {
        const int idx = t * per + k;
        if (k < per && idx < C) { cstarts[idx] = run; cursor[idx] = run; }
        run += c[k];
    }
}

// ---------------------------------------------------------------------------
// 3) Partition edges into coarse buckets (dst>>8), bucket-major staging.
//    Payload: [rel:3][dst&255:8][src:21].
// ---------------------------------------------------------------------------
#define PART_EPB 2048
__global__ __launch_bounds__(256) void partition_kernel(
    const int* __restrict__ esrc, const int* __restrict__ edst,
    const int* __restrict__ erel, int* __restrict__ cursor,
    unsigned* __restrict__ staged, int E, int C)
{
    __shared__ int lh[CHB];
    const int t = threadIdx.x;
    const int base = blockIdx.x * PART_EPB;
    const int end = min(base + PART_EPB, E);

    for (int i = t; i < C; i += 256) lh[i] = 0;
    __syncthreads();
    for (int i = base + t; i < end; i += 256)
        atomicAdd(&lh[edst[i] >> 8], 1);
    __syncthreads();
    for (int i = t; i < C; i += 256) {
        const int c = lh[i];
        lh[i] = c ? atomicAdd(&cursor[i], c) : 0;
    }
    __syncthreads();
    for (int i = base + t; i < end; i += 256) {
        const int d = edst[i];
        const int pos = atomicAdd(&lh[d >> 8], 1);
        staged[pos] = (unsigned)esrc[i] | ((unsigned)(d & 255) << 21)
                    | ((unsigned)erel[i] << 29);
    }
}

// ---------------------------------------------------------------------------
// 4) MERGED bin-sort + cast kernel. Blocks [0,C): per-bucket fine bin-sort
//    + fine scan (round-5 verified logic). Blocks [C, C+nCast): cast X->Xb,
//    [W;W0]^T->Bt. Rationale: binsort's 196 blocks leave most of 256 CUs
//    idle -> cast backfills them (true overlap), and Xb finishes writing
//    immediately before aggregate launches -> its 12.8MB gather table is
//    L2-warm (round-9 showed cold-Xb costs aggregate ~7us).
// ---------------------------------------------------------------------------
__global__ __launch_bounds__(256) void binsortcast_kernel(
    const unsigned* __restrict__ staged, const int* __restrict__ cstarts,
    int* __restrict__ starts, unsigned* __restrict__ sorted,
    int N, int E, int C,
    const float* __restrict__ X, const float* __restrict__ W,
    const float* __restrict__ W0, unsigned short* __restrict__ Xb,
    unsigned short* __restrict__ Bt, int R)
{
    __shared__ int lcur[2048];
    __shared__ int wsum[256];
    const int t = threadIdx.x;

    if (blockIdx.x >= C) {                 // ---- cast path ----
        const int ktot = (R + 1) * 128;
        const int nx = N * 32;             // float4 chunks of X
        const int idx = (blockIdx.x - C) * 256 + t;
        if (idx < nx) {
            const float4 v = ((const float4*)X)[idx];
            uint2 p;
            p.x = (unsigned)f2bf(v.x) | ((unsigned)f2bf(v.y) << 16);
            p.y = (unsigned)f2bf(v.z) | ((unsigned)f2bf(v.w) << 16);
            *(uint2*)(Xb + (size_t)idx * 4) = p;
        } else if (idx < nx + 128 * ktot) {
            const int e = idx - nx;
            const int n = e / ktot;
            const int k = e - n * ktot;
            const float v = (k < R * 128) ? W[(size_t)k * 128 + n]
                                          : W0[(size_t)(k - R * 128) * 128 + n];
            Bt[(size_t)n * ktot + k] = f2bf(v);
        }
        return;
    }

    // ---- binsort path (blocks [0,C)) ----
    const int b = blockIdx.x;
    const int d0 = b << 8;
    const int binBase = d0 * 8;
    const int nbins = (min(d0 + 256, N) - d0) * 8;
    const int base = cstarts[b];
    const int end = (b + 1 < C) ? cstarts[b + 1] : E;

    for (int i = t; i < 2048; i += 256) lcur[i] = 0;
    __syncthreads();
    for (int i = base + t; i < end; i += 256) {
        const unsigned v = staged[i];
        atomicAdd(&lcur[(int)((v >> 21) & 255u) * 8 + (int)(v >> 29)], 1);
    }
    __syncthreads();
    const int b8 = t * 8;
    int c[8]; int s = 0;
#pragma unroll
    for (int k = 0; k < 8; ++k) { c[k] = lcur[b8 + k]; s += c[k]; }
    wsum[t] = s; __syncthreads();
    for (int off = 1; off < 256; off <<= 1) {
        int x = (t >= off) ? wsum[t - off] : 0;
        __syncthreads();
        wsum[t] += x;
        __syncthreads();
    }
    int run = wsum[t] - s + base;          // exclusive prefix + bucket base
#pragma unroll
    for (int k = 0; k < 8; ++k) {
        lcur[b8 + k] = run;
        if (b8 + k < nbins) starts[binBase + b8 + k] = run;
        run += c[k];
    }
    __syncthreads();
    for (int i = base + t; i < end; i += 256) {
        const unsigned v = staged[i];
        const unsigned src = v & 0x1FFFFFu;
        const unsigned rel = v >> 29;
        const int pos = atomicAdd(&lcur[(int)((v >> 21) & 255u) * 8 + (int)rel], 1);
        sorted[pos] = src | (rel << 28);
    }
}

// ---------------------------------------------------------------------------
// 5) dst-major aggregate, one wave per dst (round-5 verified).
// ---------------------------------------------------------------------------
#define ACC(P, U) switch ((P) >> 28) {                                   \
        case 0: ax0 += bflo(U); ay0 += bfhi(U); break;                   \
        case 1: ax1 += bflo(U); ay1 += bfhi(U); break;                   \
        case 2: ax2 += bflo(U); ay2 += bfhi(U); break;                   \
        case 3: ax3 += bflo(U); ay3 += bfhi(U); break;                   \
        case 4: ax4 += bflo(U); ay4 += bfhi(U); break;                   \
        case 5: ax5 += bflo(U); ay5 += bfhi(U); break;                   \
        case 6: ax6 += bflo(U); ay6 += bfhi(U); break;                   \
        default: ax7 += bflo(U); ay7 += bfhi(U); break; }

__global__ __launch_bounds__(256) void aggregate_kernel(
    const unsigned short* __restrict__ Xb, const float* __restrict__ inv_norm,
    const unsigned* __restrict__ sorted, const int* __restrict__ starts,
    unsigned short* __restrict__ A, int N, int E)
{
    const int dst = (int)((blockIdx.x * blockDim.x + threadIdx.x) >> 6);
    if (dst >= N) return;
    const int lane = threadIdx.x & 63;

    const int start = starts[dst * 8];
    const int end = (dst + 1 < N) ? starts[dst * 8 + 8] : E;

    float ax0=0,ay0=0, ax1=0,ay1=0, ax2=0,ay2=0, ax3=0,ay3=0;
    float ax4=0,ay4=0, ax5=0,ay5=0, ax6=0,ay6=0, ax7=0,ay7=0;

    for (int cb = start; cb < end; cb += 64) {
        const int take = min(64, end - cb);
        unsigned batch = 0;
        if (cb + lane < end) batch = sorted[cb + lane];
        int j = 0;
        for (; j + 16 <= take; j += 16) {
            unsigned p[16], u[16];
#pragma unroll
            for (int q = 0; q < 16; ++q)
                p[q] = (unsigned)__builtin_amdgcn_readlane((int)batch, j + q);
#pragma unroll
            for (int q = 0; q < 16; ++q)
                u[q] = ((const unsigned*)(Xb + ((size_t)(p[q] & 0x0FFFFFFFu) << 7)))[lane];
#pragma unroll
            for (int q = 0; q < 16; ++q) { ACC(p[q], u[q]); }
        }
        for (; j + 8 <= take; j += 8) {
            unsigned p[8], u[8];
#pragma unroll
            for (int q = 0; q < 8; ++q)
                p[q] = (unsigned)__builtin_amdgcn_readlane((int)batch, j + q);
#pragma unroll
            for (int q = 0; q < 8; ++q)
                u[q] = ((const unsigned*)(Xb + ((size_t)(p[q] & 0x0FFFFFFFu) << 7)))[lane];
#pragma unroll
            for (int q = 0; q < 8; ++q) { ACC(p[q], u[q]); }
        }
        for (; j + 4 <= take; j += 4) {
            const unsigned p0 = (unsigned)__builtin_amdgcn_readlane((int)batch, j);
            const unsigned p1 = (unsigned)__builtin_amdgcn_readlane((int)batch, j + 1);
            const unsigned p2 = (unsigned)__builtin_amdgcn_readlane((int)batch, j + 2);
            const unsigned p3 = (unsigned)__builtin_amdgcn_readlane((int)batch, j + 3);
            const unsigned u0 = ((const unsigned*)(Xb + ((size_t)(p0 & 0x0FFFFFFFu) << 7)))[lane];
            const unsigned u1 = ((const unsigned*)(Xb + ((size_t)(p1 & 0x0FFFFFFFu) << 7)))[lane];
            const unsigned u2 = ((const unsigned*)(Xb + ((size_t)(p2 & 0x0FFFFFFFu) << 7)))[lane];
            const unsigned u3 = ((const unsigned*)(Xb + ((size_t)(p3 & 0x0FFFFFFFu) << 7)))[lane];
            ACC(p0, u0); ACC(p1, u1); ACC(p2, u2); ACC(p3, u3);
        }
        for (; j < take; ++j) {
            const unsigned p = (unsigned)__builtin_amdgcn_readlane((int)batch, j);
            const unsigned u = ((const unsigned*)(Xb + ((size_t)(p & 0x0FFFFFFFu) << 7)))[lane];
            ACC(p, u);
        }
    }

    const float nv_l = (lane < 8) ? inv_norm[(size_t)lane * N + dst] : 0.f;

    unsigned short* Arow = A + (size_t)dst * 1024 + lane * 2;   // pitch R*128
    {
        float s;
        s = readlane_f(nv_l, 0); *(unsigned*)(Arow + 0*128) = (unsigned)f2bf(ax0*s) | ((unsigned)f2bf(ay0*s) << 16);
        s = readlane_f(nv_l, 1); *(unsigned*)(Arow + 1*128) = (unsigned)f2bf(ax1*s) | ((unsigned)f2bf(ay1*s) << 16);
        s = readlane_f(nv_l, 2); *(unsigned*)(Arow + 2*128) = (unsigned)f2bf(ax2*s) | ((unsigned)f2bf(ay2*s) << 16);
        s = readlane_f(nv_l, 3); *(unsigned*)(Arow + 3*128) = (unsigned)f2bf(ax3*s) | ((unsigned)f2bf(ay3*s) << 16);
        s = readlane_f(nv_l, 4); *(unsigned*)(Arow + 4*128) = (unsigned)f2bf(ax4*s) | ((unsigned)f2bf(ay4*s) << 16);
        s = readlane_f(nv_l, 5); *(unsigned*)(Arow + 5*128) = (unsigned)f2bf(ax5*s) | ((unsigned)f2bf(ay5*s) << 16);
        s = readlane_f(nv_l, 6); *(unsigned*)(Arow + 6*128) = (unsigned)f2bf(ax6*s) | ((unsigned)f2bf(ay6*s) << 16);
        s = readlane_f(nv_l, 7); *(unsigned*)(Arow + 7*128) = (unsigned)f2bf(ax7*s) | ((unsigned)f2bf(ay7*s) << 16);
    }
}

// ---------------------------------------------------------------------------
// 6) bf16 MFMA GEMM: out[M,128] = [A | Xb][M,KT] @ Bt[128,KT]^T (fp32 out)
//    BM=128, BN=128, BK=64; 512 threads = 8 waves; double-buffered LDS with
//    early-issued register staging (round-1 verified win; round-5 config).
// ---------------------------------------------------------------------------
template <int KT>
__global__ __launch_bounds__(512) void gemm_kernel(
    const unsigned short* __restrict__ A, const unsigned short* __restrict__ Xb,
    const unsigned short* __restrict__ Bt, float* __restrict__ out, int M)
{
    constexpr int NI = KT / 64;            // 18 K-steps
    constexpr int NA = (KT - 128) / 64;    // 16 from A, last 2 from Xb
    __shared__ unsigned short Asw[2][128 * 64];   // 2 x 16 KB
    __shared__ unsigned short Bsw[2][128 * 64];   // 2 x 16 KB

    const int tid = threadIdx.x;
    const int wave = tid >> 6;             // 0..7
    const int lane = tid & 63;
    const int ln = lane & 15, quad = lane >> 4;
    const int wm = wave & 3;               // m-wave: 4 x 32 rows
    const int wn = wave >> 2;              // n-wave: 2 x 64 cols
    const int m0 = blockIdx.x * 128;

    const int sr = tid >> 2;               // 0..127 (row of both tiles)
    const int sq = tid & 3;
    int am = m0 + sr; if (am >= M) am = M - 1;
    const unsigned short* Ag = A  + (size_t)am * (KT - 128) + sq * 16;
    const unsigned short* Xg = Xb + (size_t)am * 128 + sq * 16;
    const unsigned short* Bg = Bt + (size_t)sr * KT + sq * 16;

    const int wofs0 = sr * 64 + ((((sq << 1) + 0) ^ (sr & 7)) << 3);
    const int wofs1 = sr * 64 + ((((sq << 1) + 1) ^ (sr & 7)) << 3);

    f32x4 acc[8] = {};
    short8 ra0, ra1, rb0, rb1;

    auto load_regs = [&](int ko) {
        const unsigned short* as = (ko < NA) ? (Ag + ko * 64) : (Xg + (ko - NA) * 64);
        ra0 = *(const short8*)(as);
        ra1 = *(const short8*)(as + 8);
        const unsigned short* bs = Bg + ko * 64;
        rb0 = *(const short8*)(bs);
        rb1 = *(const short8*)(bs + 8);
    };
    auto write_lds = [&](int buf) {
        *(short8*)&Asw[buf][wofs0] = ra0;
        *(short8*)&Asw[buf][wofs1] = ra1;
        *(short8*)&Bsw[buf][wofs0] = rb0;
        *(short8*)&Bsw[buf][wofs1] = rb1;
    };

    load_regs(0);
    write_lds(0);
    __syncthreads();

    int cur = 0;
#pragma unroll
    for (int ko = 0; ko < NI; ++ko) {
        if (ko + 1 < NI) load_regs(ko + 1);       // issue next tile's loads early
        __builtin_amdgcn_sched_barrier(0);        // keep loads above MFMA phase
#pragma unroll
        for (int ks = 0; ks < 2; ++ks) {          // two 16x16x32 K-slices
            short8 af[2], bf[4];
#pragma unroll
            for (int mi = 0; mi < 2; ++mi) {
                const int r = wm * 32 + mi * 16 + ln;
                af[mi] = *(const short8*)&Asw[cur][r * 64 + ((((ks << 2) + quad) ^ (r & 7)) << 3)];
            }
#pragma unroll
            for (int ci = 0; ci < 4; ++ci) {
                const int r = wn * 64 + ci * 16 + ln;
                bf[ci] = *(const short8*)&Bsw[cur][r * 64 + ((((ks << 2) + quad) ^ (r & 7)) << 3)];
            }
#pragma unroll
            for (int mi = 0; mi < 2; ++mi)
#pragma unroll
                for (int ci = 0; ci < 4; ++ci)
                    acc[mi * 4 + ci] = __builtin_amdgcn_mfma_f32_16x16x32_bf16(
                        af[mi], bf[ci], acc[mi * 4 + ci], 0, 0, 0);
        }
        __builtin_amdgcn_sched_barrier(0);        // keep ds_write (vmcnt wait) below MFMA
        if (ko + 1 < NI) write_lds(cur ^ 1);      // implicit s_waitcnt vmcnt here
        __syncthreads();
        cur ^= 1;
    }

#pragma unroll
    for (int mi = 0; mi < 2; ++mi)
#pragma unroll
        for (int ci = 0; ci < 4; ++ci)
#pragma unroll
            for (int rg = 0; rg < 4; ++rg) {
                const int row = m0 + wm * 32 + mi * 16 + quad * 4 + rg;
                if (row < M)
                    out[(size_t)row * 128 + wn * 64 + ci * 16 + ln] = acc[mi * 4 + ci][rg];
            }
}

// Generic-K fallback (runtime loop bound), slow but correct
__global__ __launch_bounds__(256) void gemm_kernel_rt(
    const unsigned short* __restrict__ A, const unsigned short* __restrict__ Xb,
    const unsigned short* __restrict__ Bt, float* __restrict__ out,
    int M, int ktot)
{
    const int tid = threadIdx.x;
    const int wave = tid >> 6;
    const int lane = tid & 63;
    const int ln = lane & 15, quad = lane >> 4;
    const int m0 = blockIdx.x * 64 + wave * 16;
    int m = m0 + ln; if (m >= M) m = M - 1;
    const unsigned short* Arow = A + (size_t)m * (ktot - 128) + quad * 8;
    const unsigned short* Xrow = Xb + (size_t)m * 128 + quad * 8;
    const unsigned short* Bbase = Bt + (size_t)ln * ktot + quad * 8;

    f32x4 acc[8] = {};
    for (int kb = 0; kb < (ktot >> 5); ++kb) {
        const int k0 = kb << 5;
        const unsigned short* asrc = (k0 < ktot - 128) ? (Arow + k0) : (Xrow + (k0 - (ktot - 128)));
        const short8 a = *(const short8*)asrc;
#pragma unroll
        for (int c = 0; c < 8; ++c) {
            const short8 b = *(const short8*)(Bbase + (size_t)c * 16 * ktot + k0);
            acc[c] = __builtin_amdgcn_mfma_f32_16x16x32_bf16(a, b, acc[c], 0, 0, 0);
        }
    }
#pragma unroll
    for (int c = 0; c < 8; ++c) {
#pragma unroll
        for (int rg = 0; rg < 4; ++rg) {
            const int row = m0 + quad * 4 + rg;
            if (row < M) out[(size_t)row * 128 + c * 16 + ln] = acc[c][rg];
        }
    }
}

// ---------------------------------------------------------------------------
extern "C" void kernel_launch(void* const* d_in, const int* in_sizes, int n_in,
                              void* d_out, int out_size, void* d_ws, size_t ws_size,
                              hipStream_t stream) {
    const float* X        = (const float*)d_in[0];
    const float* W        = (const float*)d_in[1];
    const float* W0       = (const float*)d_in[2];
    const float* inv_norm = (const float*)d_in[3];
    const int*   esrc     = (const int*)d_in[4];
    const int*   edst     = (const int*)d_in[5];
    const int*   erel     = (const int*)d_in[6];
    float* out = (float*)d_out;

    const int N  = in_sizes[0] / 128;     // 50000
    const int E  = in_sizes[4];           // 800000
    const int R  = in_sizes[3] / N;       // 8
    const int KB = N * 8;                 // 400000 bins (dst*8+rel)
    const int ktot = (R + 1) * 128;       // 1152
    const int C  = (N + 255) >> 8;        // 196 coarse buckets (dst>>8)

    char* ws = (char*)d_ws;
    size_t off = 0;
    auto alloc = [&](size_t bytes) -> char* {
        char* p = ws + off; off = (off + bytes + 255) & ~(size_t)255; return p;
    };
    unsigned short* A         = (unsigned short*)alloc((size_t)N * R * 128 * 2); // 102.4 MB
    unsigned short* Xb        = (unsigned short*)alloc((size_t)N * 128 * 2);     // 12.8 MB
    unsigned short* Bt        = (unsigned short*)alloc((size_t)128 * ktot * 2);  // 0.3 MB
    int*            ccounts   = (int*)alloc((size_t)C * 4);
    int*            cstarts   = (int*)alloc((size_t)C * 4);
    int*            cursor    = (int*)alloc((size_t)C * 4);
    int*            starts    = (int*)alloc((size_t)KB * 4);                     // 1.6 MB
    unsigned*       staged    = (unsigned*)alloc((size_t)E * 4);                 // 3.2 MB
    unsigned*       sorted    = (unsigned*)alloc((size_t)E * 4);                 // 3.2 MB
    (void)ws_size;

    const int nEdgeBlocks = (E + 2047) / 2048;                    // 391
    const int nCastBlocks = (N * 32 + 128 * ktot + 255) / 256;    // ~6827

    hipMemsetAsync(ccounts, 0, (size_t)C * 4, stream);
    chist_kernel<<<nEdgeBlocks, 256, 0, stream>>>(edst, ccounts, E, C);
    cscan_kernel<<<1, 256, 0, stream>>>(ccounts, cstarts, cursor, C);
    partition_kernel<<<nEdgeBlocks, 256, 0, stream>>>(esrc, edst, erel, cursor, staged, E, C);
    binsortcast_kernel<<<C + nCastBlocks, 256, 0, stream>>>(
        staged, cstarts, starts, sorted, N, E, C, X, W, W0, Xb, Bt, R);
    aggregate_kernel<<<(N + 3) / 4, 256, 0, stream>>>(Xb, inv_norm, sorted, starts, A, N, E);
    if (ktot == 1152)
        gemm_kernel<1152><<<(N + 127) / 128, 512, 0, stream>>>(A, Xb, Bt, out, N);
    else
        gemm_kernel_rt<<<(N + 63) / 64, 256, 0, stream>>>(A, Xb, Bt, out, N, ktot);
}

// Round 11
// 200.773 us; speedup vs baseline: 1.0083x; 1.0083x over previous
//
#include <hip/hip_runtime.h>

typedef __attribute__((ext_vector_type(8))) short short8;
typedef __attribute__((ext_vector_type(4))) float f32x4;

__device__ __forceinline__ unsigned short f2bf(float f) {
    unsigned u = __float_as_uint(f);
    u += 0x7FFF + ((u >> 16) & 1);          // round-to-nearest-even
    return (unsigned short)(u >> 16);
}

__device__ __forceinline__ float readlane_f(float v, int l) {
    return __int_as_float(__builtin_amdgcn_readlane(__float_as_int(v), l));
}

__device__ __forceinline__ float bflo(unsigned u) { return __uint_as_float(u << 16); }
__device__ __forceinline__ float bfhi(unsigned u) { return __uint_as_float(u & 0xFFFF0000u); }

// ---------------------------------------------------------------------------
// 1) Coarse histogram over bucket = dst>>8 (round-5 verified form).
// ---------------------------------------------------------------------------
#define CHB 2048
__global__ __launch_bounds__(256) void chist_kernel(
    const int* __restrict__ edst, int* __restrict__ ccounts, int E, int C)
{
    __shared__ int lh[CHB];
    const int t = threadIdx.x;
    for (int i = t; i < C; i += 256) lh[i] = 0;
    __syncthreads();
    const int base = blockIdx.x * 2048;
    const int end = min(base + 2048, E);
    for (int i = base + t; i < end; i += 256)
        atomicAdd(&lh[edst[i] >> 8], 1);
    __syncthreads();
    for (int i = t; i < C; i += 256)
        if (lh[i]) atomicAdd(&ccounts[i], lh[i]);
}

// ---------------------------------------------------------------------------
// 2) Single-block exclusive scan over C coarse counts -> cstarts + cursor.
// ---------------------------------------------------------------------------
__global__ __launch_bounds__(256) void cscan_kernel(
    const int* __restrict__ ccounts, int* __restrict__ cstarts,
    int* __restrict__ cursor, int C)
{
    __shared__ int sd[256];
    const int t = threadIdx.x;
    const int per = (C + 255) >> 8;        // items per thread (<=8 for C<=2048)
    int c[8]; int s = 0;
#pragma unroll
    for (int k = 0; k < 8; ++k) {
        const int idx = t * per + k;
        c[k] = (k < per && idx < C) ? ccounts[idx] : 0;
        s += c[k];
    }
    sd[t] = s; __syncthreads();
    for (int off = 1; off < 256; off <<= 1) {
        int x = (t >= off) ? sd[t - off] : 0;
        __syncthreads();
        sd[t] += x;
        __syncthreads();
    }
    int run = sd[t] - s;
#pragma unroll
    for (int k = 0; k < 8; ++k) {
        const int idx = t * per + k;
        if (k < per && idx < C) { cstarts[idx] = run; cursor[idx] = run; }
        run += c[k];
    }
}

// ---------------------------------------------------------------------------
// 3) Partition edges into coarse buckets (dst>>8), bucket-major staging.
//    Payload: [rel:3][dst&255:8][src:21].
// ---------------------------------------------------------------------------
#define PART_EPB 2048
__global__ __launch_bounds__(256) void partition_kernel(
    const int* __restrict__ esrc, const int* __restrict__ edst,
    const int* __restrict__ erel, int* __restrict__ cursor,
    unsigned* __restrict__ staged, int E, int C)
{
    __shared__ int lh[CHB];
    const int t = threadIdx.x;
    const int base = blockIdx.x * PART_EPB;
    const int end = min(base + PART_EPB, E);

    for (int i = t; i < C; i += 256) lh[i] = 0;
    __syncthreads();
    for (int i = base + t; i < end; i += 256)
        atomicAdd(&lh[edst[i] >> 8], 1);
    __syncthreads();
    for (int i = t; i < C; i += 256) {
        const int c = lh[i];
        lh[i] = c ? atomicAdd(&cursor[i], c) : 0;
    }
    __syncthreads();
    for (int i = base + t; i < end; i += 256) {
        const int d = edst[i];
        const int pos = atomicAdd(&lh[d >> 8], 1);
        staged[pos] = (unsigned)esrc[i] | ((unsigned)(d & 255) << 21)
                    | ((unsigned)erel[i] << 29);
    }
}

// ---------------------------------------------------------------------------
// 4) MERGED bin-sort + cast kernel (round-9/10 verified: cast backfills the
//    idle CUs during binsort's 196 blocks AND leaves Xb L2-warm for the
//    aggregate launch that follows).
// ---------------------------------------------------------------------------
__global__ __launch_bounds__(256) void binsortcast_kernel(
    const unsigned* __restrict__ staged, const int* __restrict__ cstarts,
    int* __restrict__ starts, unsigned* __restrict__ sorted,
    int N, int E, int C,
    const float* __restrict__ X, const float* __restrict__ W,
    const float* __restrict__ W0, unsigned short* __restrict__ Xb,
    unsigned short* __restrict__ Bt, int R)
{
    __shared__ int lcur[2048];
    __shared__ int wsum[256];
    const int t = threadIdx.x;

    if (blockIdx.x >= C) {                 // ---- cast path ----
        const int ktot = (R + 1) * 128;
        const int nx = N * 32;             // float4 chunks of X
        const int idx = (blockIdx.x - C) * 256 + t;
        if (idx < nx) {
            const float4 v = ((const float4*)X)[idx];
            uint2 p;
            p.x = (unsigned)f2bf(v.x) | ((unsigned)f2bf(v.y) << 16);
            p.y = (unsigned)f2bf(v.z) | ((unsigned)f2bf(v.w) << 16);
            *(uint2*)(Xb + (size_t)idx * 4) = p;
        } else if (idx < nx + 128 * ktot) {
            const int e = idx - nx;
            const int n = e / ktot;
            const int k = e - n * ktot;
            const float v = (k < R * 128) ? W[(size_t)k * 128 + n]
                                          : W0[(size_t)(k - R * 128) * 128 + n];
            Bt[(size_t)n * ktot + k] = f2bf(v);
        }
        return;
    }

    // ---- binsort path (blocks [0,C)) ----
    const int b = blockIdx.x;
    const int d0 = b << 8;
    const int binBase = d0 * 8;
    const int nbins = (min(d0 + 256, N) - d0) * 8;
    const int base = cstarts[b];
    const int end = (b + 1 < C) ? cstarts[b + 1] : E;

    for (int i = t; i < 2048; i += 256) lcur[i] = 0;
    __syncthreads();
    for (int i = base + t; i < end; i += 256) {
        const unsigned v = staged[i];
        atomicAdd(&lcur[(int)((v >> 21) & 255u) * 8 + (int)(v >> 29)], 1);
    }
    __syncthreads();
    const int b8 = t * 8;
    int c[8]; int s = 0;
#pragma unroll
    for (int k = 0; k < 8; ++k) { c[k] = lcur[b8 + k]; s += c[k]; }
    wsum[t] = s; __syncthreads();
    for (int off = 1; off < 256; off <<= 1) {
        int x = (t >= off) ? wsum[t - off] : 0;
        __syncthreads();
        wsum[t] += x;
        __syncthreads();
    }
    int run = wsum[t] - s + base;          // exclusive prefix + bucket base
#pragma unroll
    for (int k = 0; k < 8; ++k) {
        lcur[b8 + k] = run;
        if (b8 + k < nbins) starts[binBase + b8 + k] = run;
        run += c[k];
    }
    __syncthreads();
    for (int i = base + t; i < end; i += 256) {
        const unsigned v = staged[i];
        const unsigned src = v & 0x1FFFFFu;
        const unsigned rel = v >> 29;
        const int pos = atomicAdd(&lcur[(int)((v >> 21) & 255u) * 8 + (int)rel], 1);
        sorted[pos] = src | (rel << 28);
    }
}

// ---------------------------------------------------------------------------
// 5) dst-major aggregate, one wave per dst (round-5 verified).
// ---------------------------------------------------------------------------
#define ACC(P, U) switch ((P) >> 28) {                                   \
        case 0: ax0 += bflo(U); ay0 += bfhi(U); break;                   \
        case 1: ax1 += bflo(U); ay1 += bfhi(U); break;                   \
        case 2: ax2 += bflo(U); ay2 += bfhi(U); break;                   \
        case 3: ax3 += bflo(U); ay3 += bfhi(U); break;                   \
        case 4: ax4 += bflo(U); ay4 += bfhi(U); break;                   \
        case 5: ax5 += bflo(U); ay5 += bfhi(U); break;                   \
        case 6: ax6 += bflo(U); ay6 += bfhi(U); break;                   \
        default: ax7 += bflo(U); ay7 += bfhi(U); break; }

__global__ __launch_bounds__(256) void aggregate_kernel(
    const unsigned short* __restrict__ Xb, const float* __restrict__ inv_norm,
    const unsigned* __restrict__ sorted, const int* __restrict__ starts,
    unsigned short* __restrict__ A, int N, int E)
{
    const int dst = (int)((blockIdx.x * blockDim.x + threadIdx.x) >> 6);
    if (dst >= N) return;
    const int lane = threadIdx.x & 63;

    const int start = starts[dst * 8];
    const int end = (dst + 1 < N) ? starts[dst * 8 + 8] : E;

    float ax0=0,ay0=0, ax1=0,ay1=0, ax2=0,ay2=0, ax3=0,ay3=0;
    float ax4=0,ay4=0, ax5=0,ay5=0, ax6=0,ay6=0, ax7=0,ay7=0;

    for (int cb = start; cb < end; cb += 64) {
        const int take = min(64, end - cb);
        unsigned batch = 0;
        if (cb + lane < end) batch = sorted[cb + lane];
        int j = 0;
        for (; j + 16 <= take; j += 16) {
            unsigned p[16], u[16];
#pragma unroll
            for (int q = 0; q < 16; ++q)
                p[q] = (unsigned)__builtin_amdgcn_readlane((int)batch, j + q);
#pragma unroll
            for (int q = 0; q < 16; ++q)
                u[q] = ((const unsigned*)(Xb + ((size_t)(p[q] & 0x0FFFFFFFu) << 7)))[lane];
#pragma unroll
            for (int q = 0; q < 16; ++q) { ACC(p[q], u[q]); }
        }
        for (; j + 8 <= take; j += 8) {
            unsigned p[8], u[8];
#pragma unroll
            for (int q = 0; q < 8; ++q)
                p[q] = (unsigned)__builtin_amdgcn_readlane((int)batch, j + q);
#pragma unroll
            for (int q = 0; q < 8; ++q)
                u[q] = ((const unsigned*)(Xb + ((size_t)(p[q] & 0x0FFFFFFFu) << 7)))[lane];
#pragma unroll
            for (int q = 0; q < 8; ++q) { ACC(p[q], u[q]); }
        }
        for (; j + 4 <= take; j += 4) {
            const unsigned p0 = (unsigned)__builtin_amdgcn_readlane((int)batch, j);
            const unsigned p1 = (unsigned)__builtin_amdgcn_readlane((int)batch, j + 1);
            const unsigned p2 = (unsigned)__builtin_amdgcn_readlane((int)batch, j + 2);
            const unsigned p3 = (unsigned)__builtin_amdgcn_readlane((int)batch, j + 3);
            const unsigned u0 = ((const unsigned*)(Xb + ((size_t)(p0 & 0x0FFFFFFFu) << 7)))[lane];
            const unsigned u1 = ((const unsigned*)(Xb + ((size_t)(p1 & 0x0FFFFFFFu) << 7)))[lane];
            const unsigned u2 = ((const unsigned*)(Xb + ((size_t)(p2 & 0x0FFFFFFFu) << 7)))[lane];
            const unsigned u3 = ((const unsigned*)(Xb + ((size_t)(p3 & 0x0FFFFFFFu) << 7)))[lane];
            ACC(p0, u0); ACC(p1, u1); ACC(p2, u2); ACC(p3, u3);
        }
        for (; j < take; ++j) {
            const unsigned p = (unsigned)__builtin_amdgcn_readlane((int)batch, j);
            const unsigned u = ((const unsigned*)(Xb + ((size_t)(p & 0x0FFFFFFFu) << 7)))[lane];
            ACC(p, u);
        }
    }

    const float nv_l = (lane < 8) ? inv_norm[(size_t)lane * N + dst] : 0.f;

    unsigned short* Arow = A + (size_t)dst * 1024 + lane * 2;   // pitch R*128
    {
        float s;
        s = readlane_f(nv_l, 0); *(unsigned*)(Arow + 0*128) = (unsigned)f2bf(ax0*s) | ((unsigned)f2bf(ay0*s) << 16);
        s = readlane_f(nv_l, 1); *(unsigned*)(Arow + 1*128) = (unsigned)f2bf(ax1*s) | ((unsigned)f2bf(ay1*s) << 16);
        s = readlane_f(nv_l, 2); *(unsigned*)(Arow + 2*128) = (unsigned)f2bf(ax2*s) | ((unsigned)f2bf(ay2*s) << 16);
        s = readlane_f(nv_l, 3); *(unsigned*)(Arow + 3*128) = (unsigned)f2bf(ax3*s) | ((unsigned)f2bf(ay3*s) << 16);
        s = readlane_f(nv_l, 4); *(unsigned*)(Arow + 4*128) = (unsigned)f2bf(ax4*s) | ((unsigned)f2bf(ay4*s) << 16);
        s = readlane_f(nv_l, 5); *(unsigned*)(Arow + 5*128) = (unsigned)f2bf(ax5*s) | ((unsigned)f2bf(ay5*s) << 16);
        s = readlane_f(nv_l, 6); *(unsigned*)(Arow + 6*128) = (unsigned)f2bf(ax6*s) | ((unsigned)f2bf(ay6*s) << 16);
        s = readlane_f(nv_l, 7); *(unsigned*)(Arow + 7*128) = (unsigned)f2bf(ax7*s) | ((unsigned)f2bf(ay7*s) << 16);
    }
}

// ---------------------------------------------------------------------------
// 6) bf16 MFMA GEMM, 3-stage pipeline: out[M,128] = [A|Xb][M,KT] @ Bt^T.
//    BM=128, BN=128, BK=64; 512 threads = 8 waves. TWO register sets (A/B,
//    static names — runtime-indexed arrays would spill to scratch): at iter
//    k we ISSUE loads for tile k+2, MFMA tile k from LDS, then ds_write tile
//    k+1 from the other set. The ds_write's vmcnt wait is covered by a full
//    extra K-step (~600 cyc) instead of one MFMA phase (~155 cyc) — the old
//    1-step lookahead exposed most of the ~900-cyc HBM latency every step.
//    Loop unrolled 2x so set selection is compile-time.
// ---------------------------------------------------------------------------
template <int KT>
__global__ __launch_bounds__(512) void gemm_kernel(
    const unsigned short* __restrict__ A, const unsigned short* __restrict__ Xb,
    const unsigned short* __restrict__ Bt, float* __restrict__ out, int M)
{
    constexpr int NI = KT / 64;            // 18 K-steps (even)
    constexpr int NA = (KT - 128) / 64;    // 16 from A, last 2 from Xb
    __shared__ unsigned short Asw[2][128 * 64];   // 2 x 16 KB
    __shared__ unsigned short Bsw[2][128 * 64];   // 2 x 16 KB

    const int tid = threadIdx.x;
    const int wave = tid >> 6;             // 0..7
    const int lane = tid & 63;
    const int ln = lane & 15, quad = lane >> 4;
    const int wm = wave & 3;               // m-wave: 4 x 32 rows
    const int wn = wave >> 2;              // n-wave: 2 x 64 cols
    const int m0 = blockIdx.x * 128;

    const int sr = tid >> 2;               // 0..127 (row of both tiles)
    const int sq = tid & 3;
    int am = m0 + sr; if (am >= M) am = M - 1;
    const unsigned short* Ag = A  + (size_t)am * (KT - 128) + sq * 16;
    const unsigned short* Xg = Xb + (size_t)am * 128 + sq * 16;
    const unsigned short* Bg = Bt + (size_t)sr * KT + sq * 16;

    const int wofs0 = sr * 64 + ((((sq << 1) + 0) ^ (sr & 7)) << 3);
    const int wofs1 = sr * 64 + ((((sq << 1) + 1) ^ (sr & 7)) << 3);

    f32x4 acc[8] = {};
    short8 raA0, raA1, rbA0, rbA1;         // register set A
    short8 raB0, raB1, rbB0, rbB1;         // register set B

    auto loadA = [&](int ko) {
        const unsigned short* as = (ko < NA) ? (Ag + ko * 64) : (Xg + (ko - NA) * 64);
        raA0 = *(const short8*)(as);
        raA1 = *(const short8*)(as + 8);
        const unsigned short* bs = Bg + ko * 64;
        rbA0 = *(const short8*)(bs);
        rbA1 = *(const short8*)(bs + 8);
    };
    auto loadB = [&](int ko) {
        const unsigned short* as = (ko < NA) ? (Ag + ko * 64) : (Xg + (ko - NA) * 64);
        raB0 = *(const short8*)(as);
        raB1 = *(const short8*)(as + 8);
        const unsigned short* bs = Bg + ko * 64;
        rbB0 = *(const short8*)(bs);
        rbB1 = *(const short8*)(bs + 8);
    };
    auto writeA = [&](int buf) {
        *(short8*)&Asw[buf][wofs0] = raA0;
        *(short8*)&Asw[buf][wofs1] = raA1;
        *(short8*)&Bsw[buf][wofs0] = rbA0;
        *(short8*)&Bsw[buf][wofs1] = rbA1;
    };
    auto writeB = [&](int buf) {
        *(short8*)&Asw[buf][wofs0] = raB0;
        *(short8*)&Asw[buf][wofs1] = raB1;
        *(short8*)&Bsw[buf][wofs0] = rbB0;
        *(short8*)&Bsw[buf][wofs1] = rbB1;
    };
    auto mfma_phase = [&](int buf) {
#pragma unroll
        for (int ks = 0; ks < 2; ++ks) {          // two 16x16x32 K-slices
            short8 af[2], bf[4];
#pragma unroll
            for (int mi = 0; mi < 2; ++mi) {
                const int r = wm * 32 + mi * 16 + ln;
                af[mi] = *(const short8*)&Asw[buf][r * 64 + ((((ks << 2) + quad) ^ (r & 7)) << 3)];
            }
#pragma unroll
            for (int ci = 0; ci < 4; ++ci) {
                const int r = wn * 64 + ci * 16 + ln;
                bf[ci] = *(const short8*)&Bsw[buf][r * 64 + ((((ks << 2) + quad) ^ (r & 7)) << 3)];
            }
#pragma unroll
            for (int mi = 0; mi < 2; ++mi)
#pragma unroll
                for (int ci = 0; ci < 4; ++ci)
                    acc[mi * 4 + ci] = __builtin_amdgcn_mfma_f32_16x16x32_bf16(
                        af[mi], bf[ci], acc[mi * 4 + ci], 0, 0, 0);
        }
    };

    // prologue: tile0 staged to LDS; tile1 in set B (in flight)
    loadA(0);
    loadB(1);
    writeA(0);                                  // waits set-A loads only
    __syncthreads();

    int cur = 0;
#pragma unroll
    for (int kk = 0; kk < NI; kk += 2) {
        // --- iter kk: compute tile kk; set B holds tile kk+1; load kk+2 into A
        if (kk + 2 < NI) loadA(kk + 2);
        __builtin_amdgcn_sched_barrier(0);      // keep loads above MFMA phase
        mfma_phase(cur);
        __builtin_amdgcn_sched_barrier(0);      // keep ds_write below MFMA
        if (kk + 1 < NI) writeB(cur ^ 1);       // waits set-B loads (2 steps old)
        __syncthreads();
        cur ^= 1;

        // --- iter kk+1: compute tile kk+1; set A holds kk+2; load kk+3 into B
        if (kk + 1 < NI) {
            if (kk + 3 < NI) loadB(kk + 3);
            __builtin_amdgcn_sched_barrier(0);
            mfma_phase(cur);
            __builtin_amdgcn_sched_barrier(0);
            if (kk + 2 < NI) writeA(cur ^ 1);
            __syncthreads();
            cur ^= 1;
        }
    }

#pragma unroll
    for (int mi = 0; mi < 2; ++mi)
#pragma unroll
        for (int ci = 0; ci < 4; ++ci)
#pragma unroll
            for (int rg = 0; rg < 4; ++rg) {
                const int row = m0 + wm * 32 + mi * 16 + quad * 4 + rg;
                if (row < M)
                    out[(size_t)row * 128 + wn * 64 + ci * 16 + ln] = acc[mi * 4 + ci][rg];
            }
}

// Generic-K fallback (runtime loop bound), slow but correct
__global__ __launch_bounds__(256) void gemm_kernel_rt(
    const unsigned short* __restrict__ A, const unsigned short* __restrict__ Xb,
    const unsigned short* __restrict__ Bt, float* __restrict__ out,
    int M, int ktot)
{
    const int tid = threadIdx.x;
    const int wave = tid >> 6;
    const int lane = tid & 63;
    const int ln = lane & 15, quad = lane >> 4;
    const int m0 = blockIdx.x * 64 + wave * 16;
    int m = m0 + ln; if (m >= M) m = M - 1;
    const unsigned short* Arow = A + (size_t)m * (ktot - 128) + quad * 8;
    const unsigned short* Xrow = Xb + (size_t)m * 128 + quad * 8;
    const unsigned short* Bbase = Bt + (size_t)ln * ktot + quad * 8;

    f32x4 acc[8] = {};
    for (int kb = 0; kb < (ktot >> 5); ++kb) {
        const int k0 = kb << 5;
        const unsigned short* asrc = (k0 < ktot - 128) ? (Arow + k0) : (Xrow + (k0 - (ktot - 128)));
        const short8 a = *(const short8*)asrc;
#pragma unroll
        for (int c = 0; c < 8; ++c) {
            const short8 b = *(const short8*)(Bbase + (size_t)c * 16 * ktot + k0);
            acc[c] = __builtin_amdgcn_mfma_f32_16x16x32_bf16(a, b, acc[c], 0, 0, 0);
        }
    }
#pragma unroll
    for (int c = 0; c < 8; ++c) {
#pragma unroll
        for (int rg = 0; rg < 4; ++rg) {
            const int row = m0 + quad * 4 + rg;
            if (row < M) out[(size_t)row * 128 + c * 16 + ln] = acc[c][rg];
        }
    }
}

// ---------------------------------------------------------------------------
extern "C" void kernel_launch(void* const* d_in, const int* in_sizes, int n_in,
                              void* d_out, int out_size, void* d_ws, size_t ws_size,
                              hipStream_t stream) {
    const float* X        = (const float*)d_in[0];
    const float* W        = (const float*)d_in[1];
    const float* W0       = (const float*)d_in[2];
    const float* inv_norm = (const float*)d_in[3];
    const int*   esrc     = (const int*)d_in[4];
    const int*   edst     = (const int*)d_in[5];
    const int*   erel     = (const int*)d_in[6];
    float* out = (float*)d_out;

    const int N  = in_sizes[0] / 128;     // 50000
    const int E  = in_sizes[4];           // 800000
    const int R  = in_sizes[3] / N;       // 8
    const int KB = N * 8;                 // 400000 bins (dst*8+rel)
    const int ktot = (R + 1) * 128;       // 1152
    const int C  = (N + 255) >> 8;        // 196 coarse buckets (dst>>8)

    char* ws = (char*)d_ws;
    size_t off = 0;
    auto alloc = [&](size_t bytes) -> char* {
        char* p = ws + off; off = (off + bytes + 255) & ~(size_t)255; return p;
    };
    unsigned short* A         = (unsigned short*)alloc((size_t)N * R * 128 * 2); // 102.4 MB
    unsigned short* Xb        = (unsigned short*)alloc((size_t)N * 128 * 2);     // 12.8 MB
    unsigned short* Bt        = (unsigned short*)alloc((size_t)128 * ktot * 2);  // 0.3 MB
    int*            ccounts   = (int*)alloc((size_t)C * 4);
    int*            cstarts   = (int*)alloc((size_t)C * 4);
    int*            cursor    = (int*)alloc((size_t)C * 4);
    int*            starts    = (int*)alloc((size_t)KB * 4);                     // 1.6 MB
    unsigned*       staged    = (unsigned*)alloc((size_t)E * 4);                 // 3.2 MB
    unsigned*       sorted    = (unsigned*)alloc((size_t)E * 4);                 // 3.2 MB
    (void)ws_size;

    const int nEdgeBlocks = (E + 2047) / 2048;                    // 391
    const int nCastBlocks = (N * 32 + 128 * ktot + 255) / 256;    // ~6827

    hipMemsetAsync(ccounts, 0, (size_t)C * 4, stream);
    chist_kernel<<<nEdgeBlocks, 256, 0, stream>>>(edst, ccounts, E, C);
    cscan_kernel<<<1, 256, 0, stream>>>(ccounts, cstarts, cursor, C);
    partition_kernel<<<nEdgeBlocks, 256, 0, stream>>>(esrc, edst, erel, cursor, staged, E, C);
    binsortcast_kernel<<<C + nCastBlocks, 256, 0, stream>>>(
        staged, cstarts, starts, sorted, N, E, C, X, W, W0, Xb, Bt, R);
    aggregate_kernel<<<(N + 3) / 4, 256, 0, stream>>>(Xb, inv_norm, sorted, starts, A, N, E);
    if (ktot == 1152)
        gemm_kernel<1152><<<(N + 127) / 128, 512, 0, stream>>>(A, Xb, Bt, out, N);
    else
        gemm_kernel_rt<<<(N + 63) / 64, 256, 0, stream>>>(A, Xb, Bt, out, N, ktot);
}

// Round 12
// 194.951 us; speedup vs baseline: 1.0384x; 1.0299x over previous
//
#include <hip/hip_runtime.h>

typedef __attribute__((ext_vector_type(8))) short short8;
typedef __attribute__((ext_vector_type(4))) float f32x4;

__device__ __forceinline__ unsigned short f2bf(float f) {
    unsigned u = __float_as_uint(f);
    u += 0x7FFF + ((u >> 16) & 1);          // round-to-nearest-even
    return (unsigned short)(u >> 16);
}

__device__ __forceinline__ float readlane_f(float v, int l) {
    return __int_as_float(__builtin_amdgcn_readlane(__float_as_int(v), l));
}

__device__ __forceinline__ float bflo(unsigned u) { return __uint_as_float(u << 16); }
__device__ __forceinline__ float bfhi(unsigned u) { return __uint_as_float(u & 0xFFFF0000u); }

// global -> LDS direct copy, 16B per lane. LDS dest is wave-uniform base +
// lane*16 (HW rule, m104); global src is per-lane (so swizzle lives there).
__device__ __forceinline__ void gld_lds16(const void* g, void* l) {
    __builtin_amdgcn_global_load_lds(
        (const __attribute__((address_space(1))) unsigned*)g,
        (__attribute__((address_space(3))) unsigned*)l, 16, 0, 0);
}

// ---------------------------------------------------------------------------
// 1) Coarse histogram over bucket = dst>>8 (round-5 verified form).
// ---------------------------------------------------------------------------
#define CHB 2048
__global__ __launch_bounds__(256) void chist_kernel(
    const int* __restrict__ edst, int* __restrict__ ccounts, int E, int C)
{
    __shared__ int lh[CHB];
    const int t = threadIdx.x;
    for (int i = t; i < C; i += 256) lh[i] = 0;
    __syncthreads();
    const int base = blockIdx.x * 2048;
    const int end = min(base + 2048, E);
    for (int i = base + t; i < end; i += 256)
        atomicAdd(&lh[edst[i] >> 8], 1);
    __syncthreads();
    for (int i = t; i < C; i += 256)
        if (lh[i]) atomicAdd(&ccounts[i], lh[i]);
}

// ---------------------------------------------------------------------------
// 2) Single-block exclusive scan over C coarse counts -> cstarts + cursor.
// ---------------------------------------------------------------------------
__global__ __launch_bounds__(256) void cscan_kernel(
    const int* __restrict__ ccounts, int* __restrict__ cstarts,
    int* __restrict__ cursor, int C)
{
    __shared__ int sd[256];
    const int t = threadIdx.x;
    const int per = (C + 255) >> 8;        // items per thread (<=8 for C<=2048)
    int c[8]; int s = 0;
#pragma unroll
    for (int k = 0; k < 8; ++k) {
        const int idx = t * per + k;
        c[k] = (k < per && idx < C) ? ccounts[idx] : 0;
        s += c[k];
    }
    sd[t] = s; __syncthreads();
    for (int off = 1; off < 256; off <<= 1) {
        int x = (t >= off) ? sd[t - off] : 0;
        __syncthreads();
        sd[t] += x;
        __syncthreads();
    }
    int run = sd[t] - s;
#pragma unroll
    for (int k = 0; k < 8; ++k) {
        const int idx = t * per + k;
        if (k < per && idx < C) { cstarts[idx] = run; cursor[idx] = run; }
        run += c[k];
    }
}

// ---------------------------------------------------------------------------
// 3) Partition edges into coarse buckets (dst>>8), bucket-major staging.
//    Payload: [rel:3][dst&255:8][src:21].
// ---------------------------------------------------------------------------
#define PART_EPB 2048
__global__ __launch_bounds__(256) void partition_kernel(
    const int* __restrict__ esrc, const int* __restrict__ edst,
    const int* __restrict__ erel, int* __restrict__ cursor,
    unsigned* __restrict__ staged, int E, int C)
{
    __shared__ int lh[CHB];
    const int t = threadIdx.x;
    const int base = blockIdx.x * PART_EPB;
    const int end = min(base + PART_EPB, E);

    for (int i = t; i < C; i += 256) lh[i] = 0;
    __syncthreads();
    for (int i = base + t; i < end; i += 256)
        atomicAdd(&lh[edst[i] >> 8], 1);
    __syncthreads();
    for (int i = t; i < C; i += 256) {
        const int c = lh[i];
        lh[i] = c ? atomicAdd(&cursor[i], c) : 0;
    }
    __syncthreads();
    for (int i = base + t; i < end; i += 256) {
        const int d = edst[i];
        const int pos = atomicAdd(&lh[d >> 8], 1);
        staged[pos] = (unsigned)esrc[i] | ((unsigned)(d & 255) << 21)
                    | ((unsigned)erel[i] << 29);
    }
}

// ---------------------------------------------------------------------------
// 4) MERGED bin-sort + cast kernel (round-9/10 verified: cast backfills the
//    idle CUs during binsort's 196 blocks AND leaves Xb L2-warm for the
//    aggregate launch that follows).
// ---------------------------------------------------------------------------
__global__ __launch_bounds__(256) void binsortcast_kernel(
    const unsigned* __restrict__ staged, const int* __restrict__ cstarts,
    int* __restrict__ starts, unsigned* __restrict__ sorted,
    int N, int E, int C,
    const float* __restrict__ X, const float* __restrict__ W,
    const float* __restrict__ W0, unsigned short* __restrict__ Xb,
    unsigned short* __restrict__ Bt, int R)
{
    __shared__ int lcur[2048];
    __shared__ int wsum[256];
    const int t = threadIdx.x;

    if (blockIdx.x >= C) {                 // ---- cast path ----
        const int ktot = (R + 1) * 128;
        const int nx = N * 32;             // float4 chunks of X
        const int idx = (blockIdx.x - C) * 256 + t;
        if (idx < nx) {
            const float4 v = ((const float4*)X)[idx];
            uint2 p;
            p.x = (unsigned)f2bf(v.x) | ((unsigned)f2bf(v.y) << 16);
            p.y = (unsigned)f2bf(v.z) | ((unsigned)f2bf(v.w) << 16);
            *(uint2*)(Xb + (size_t)idx * 4) = p;
        } else if (idx < nx + 128 * ktot) {
            const int e = idx - nx;
            const int n = e / ktot;
            const int k = e - n * ktot;
            const float v = (k < R * 128) ? W[(size_t)k * 128 + n]
                                          : W0[(size_t)(k - R * 128) * 128 + n];
            Bt[(size_t)n * ktot + k] = f2bf(v);
        }
        return;
    }

    // ---- binsort path (blocks [0,C)) ----
    const int b = blockIdx.x;
    const int d0 = b << 8;
    const int binBase = d0 * 8;
    const int nbins = (min(d0 + 256, N) - d0) * 8;
    const int base = cstarts[b];
    const int end = (b + 1 < C) ? cstarts[b + 1] : E;

    for (int i = t; i < 2048; i += 256) lcur[i] = 0;
    __syncthreads();
    for (int i = base + t; i < end; i += 256) {
        const unsigned v = staged[i];
        atomicAdd(&lcur[(int)((v >> 21) & 255u) * 8 + (int)(v >> 29)], 1);
    }
    __syncthreads();
    const int b8 = t * 8;
    int c[8]; int s = 0;
#pragma unroll
    for (int k = 0; k < 8; ++k) { c[k] = lcur[b8 + k]; s += c[k]; }
    wsum[t] = s; __syncthreads();
    for (int off = 1; off < 256; off <<= 1) {
        int x = (t >= off) ? wsum[t - off] : 0;
        __syncthreads();
        wsum[t] += x;
        __syncthreads();
    }
    int run = wsum[t] - s + base;          // exclusive prefix + bucket base
#pragma unroll
    for (int k = 0; k < 8; ++k) {
        lcur[b8 + k] = run;
        if (b8 + k < nbins) starts[binBase + b8 + k] = run;
        run += c[k];
    }
    __syncthreads();
    for (int i = base + t; i < end; i += 256) {
        const unsigned v = staged[i];
        const unsigned src = v & 0x1FFFFFu;
        const unsigned rel = v >> 29;
        const int pos = atomicAdd(&lcur[(int)((v >> 21) & 255u) * 8 + (int)rel], 1);
        sorted[pos] = src | (rel << 28);
    }
}

// ---------------------------------------------------------------------------
// 5) dst-major aggregate, one wave per dst (round-5 verified).
// ---------------------------------------------------------------------------
#define ACC(P, U) switch ((P) >> 28) {                                   \
        case 0: ax0 += bflo(U); ay0 += bfhi(U); break;                   \
        case 1: ax1 += bflo(U); ay1 += bfhi(U); break;                   \
        case 2: ax2 += bflo(U); ay2 += bfhi(U); break;                   \
        case 3: ax3 += bflo(U); ay3 += bfhi(U); break;                   \
        case 4: ax4 += bflo(U); ay4 += bfhi(U); break;                   \
        case 5: ax5 += bflo(U); ay5 += bfhi(U); break;                   \
        case 6: ax6 += bflo(U); ay6 += bfhi(U); break;                   \
        default: ax7 += bflo(U); ay7 += bfhi(U); break; }

__global__ __launch_bounds__(256) void aggregate_kernel(
    const unsigned short* __restrict__ Xb, const float* __restrict__ inv_norm,
    const unsigned* __restrict__ sorted, const int* __restrict__ starts,
    unsigned short* __restrict__ A, int N, int E)
{
    const int dst = (int)((blockIdx.x * blockDim.x + threadIdx.x) >> 6);
    if (dst >= N) return;
    const int lane = threadIdx.x & 63;

    const int start = starts[dst * 8];
    const int end = (dst + 1 < N) ? starts[dst * 8 + 8] : E;

    float ax0=0,ay0=0, ax1=0,ay1=0, ax2=0,ay2=0, ax3=0,ay3=0;
    float ax4=0,ay4=0, ax5=0,ay5=0, ax6=0,ay6=0, ax7=0,ay7=0;

    for (int cb = start; cb < end; cb += 64) {
        const int take = min(64, end - cb);
        unsigned batch = 0;
        if (cb + lane < end) batch = sorted[cb + lane];
        int j = 0;
        for (; j + 16 <= take; j += 16) {
            unsigned p[16], u[16];
#pragma unroll
            for (int q = 0; q < 16; ++q)
                p[q] = (unsigned)__builtin_amdgcn_readlane((int)batch, j + q);
#pragma unroll
            for (int q = 0; q < 16; ++q)
                u[q] = ((const unsigned*)(Xb + ((size_t)(p[q] & 0x0FFFFFFFu) << 7)))[lane];
#pragma unroll
            for (int q = 0; q < 16; ++q) { ACC(p[q], u[q]); }
        }
        for (; j + 8 <= take; j += 8) {
            unsigned p[8], u[8];
#pragma unroll
            for (int q = 0; q < 8; ++q)
                p[q] = (unsigned)__builtin_amdgcn_readlane((int)batch, j + q);
#pragma unroll
            for (int q = 0; q < 8; ++q)
                u[q] = ((const unsigned*)(Xb + ((size_t)(p[q] & 0x0FFFFFFFu) << 7)))[lane];
#pragma unroll
            for (int q = 0; q < 8; ++q) { ACC(p[q], u[q]); }
        }
        for (; j + 4 <= take; j += 4) {
            const unsigned p0 = (unsigned)__builtin_amdgcn_readlane((int)batch, j);
            const unsigned p1 = (unsigned)__builtin_amdgcn_readlane((int)batch, j + 1);
            const unsigned p2 = (unsigned)__builtin_amdgcn_readlane((int)batch, j + 2);
            const unsigned p3 = (unsigned)__builtin_amdgcn_readlane((int)batch, j + 3);
            const unsigned u0 = ((const unsigned*)(Xb + ((size_t)(p0 & 0x0FFFFFFFu) << 7)))[lane];
            const unsigned u1 = ((const unsigned*)(Xb + ((size_t)(p1 & 0x0FFFFFFFu) << 7)))[lane];
            const unsigned u2 = ((const unsigned*)(Xb + ((size_t)(p2 & 0x0FFFFFFFu) << 7)))[lane];
            const unsigned u3 = ((const unsigned*)(Xb + ((size_t)(p3 & 0x0FFFFFFFu) << 7)))[lane];
            ACC(p0, u0); ACC(p1, u1); ACC(p2, u2); ACC(p3, u3);
        }
        for (; j < take; ++j) {
            const unsigned p = (unsigned)__builtin_amdgcn_readlane((int)batch, j);
            const unsigned u = ((const unsigned*)(Xb + ((size_t)(p & 0x0FFFFFFFu) << 7)))[lane];
            ACC(p, u);
        }
    }

    const float nv_l = (lane < 8) ? inv_norm[(size_t)lane * N + dst] : 0.f;

    unsigned short* Arow = A + (size_t)dst * 1024 + lane * 2;   // pitch R*128
    {
        float s;
        s = readlane_f(nv_l, 0); *(unsigned*)(Arow + 0*128) = (unsigned)f2bf(ax0*s) | ((unsigned)f2bf(ay0*s) << 16);
        s = readlane_f(nv_l, 1); *(unsigned*)(Arow + 1*128) = (unsigned)f2bf(ax1*s) | ((unsigned)f2bf(ay1*s) << 16);
        s = readlane_f(nv_l, 2); *(unsigned*)(Arow + 2*128) = (unsigned)f2bf(ax2*s) | ((unsigned)f2bf(ay2*s) << 16);
        s = readlane_f(nv_l, 3); *(unsigned*)(Arow + 3*128) = (unsigned)f2bf(ax3*s) | ((unsigned)f2bf(ay3*s) << 16);
        s = readlane_f(nv_l, 4); *(unsigned*)(Arow + 4*128) = (unsigned)f2bf(ax4*s) | ((unsigned)f2bf(ay4*s) << 16);
        s = readlane_f(nv_l, 5); *(unsigned*)(Arow + 5*128) = (unsigned)f2bf(ax5*s) | ((unsigned)f2bf(ay5*s) << 16);
        s = readlane_f(nv_l, 6); *(unsigned*)(Arow + 6*128) = (unsigned)f2bf(ax6*s) | ((unsigned)f2bf(ay6*s) << 16);
        s = readlane_f(nv_l, 7); *(unsigned*)(Arow + 7*128) = (unsigned)f2bf(ax7*s) | ((unsigned)f2bf(ay7*s) << 16);
    }
}

// ---------------------------------------------------------------------------
// 6) bf16 MFMA GEMM with global_load_lds staging (m97 structure; m151:
//    gload_lds 874 vs reg-staging 646 TF at this tile size).
//    BM=128, BN=128, BK=64; 512 threads = 8 waves. Per K-step each wave
//    issues 4 gload_lds (1KB each: 8 rows x 128B): LDS dest is LINEAR
//    (wave-uniform base + lane*16, HW rule m104); the XOR chunk-swizzle
//    is applied to the per-lane GLOBAL source address instead (rule #21:
//    linear dest + inverse-swz source + swz on read). MFMA read phase
//    unchanged. Loads issue before the MFMA phase; the __syncthreads
//    vmcnt(0) drain lands after it.
// ---------------------------------------------------------------------------
template <int KT>
__global__ __launch_bounds__(512) void gemm_kernel(
    const unsigned short* __restrict__ A, const unsigned short* __restrict__ Xb,
    const unsigned short* __restrict__ Bt, float* __restrict__ out, int M)
{
    constexpr int NI = KT / 64;            // 18 K-steps
    constexpr int NA = (KT - 128) / 64;    // 16 from A, last 2 from Xb
    __shared__ unsigned short Asw[2][128 * 64];   // 2 x 16 KB
    __shared__ unsigned short Bsw[2][128 * 64];   // 2 x 16 KB

    const int tid = threadIdx.x;
    const int wave = tid >> 6;             // 0..7
    const int lane = tid & 63;
    const int ln = lane & 15, quad = lane >> 4;
    const int wm = wave & 3;               // m-wave: 4 x 32 rows
    const int wn = wave >> 2;              // n-wave: 2 x 64 cols
    const int m0 = blockIdx.x * 128;

    // staging geometry: wave stages rows [wave*16, wave*16+16) of both tiles,
    // in two 1KB gload_lds (8 rows each). lane -> (sub-row lr, chunk slot lc).
    const int lr = lane >> 3;              // 0..7
    const int lc = lane & 7;               // chunk slot 0..7
    const int r0 = wave * 16 + lr;         // rows for issue j=0
    const int r1 = wave * 16 + 8 + lr;     // rows for issue j=1
    int am0 = m0 + r0; if (am0 >= M) am0 = M - 1;
    int am1 = m0 + r1; if (am1 >= M) am1 = M - 1;
    // inverse-swizzled global sources: content for LDS slot lc of row r must
    // be global chunk (lc ^ (r&7))  (involution; read side unchanged)
    const unsigned short* pA0 = A  + (size_t)am0 * (KT - 128) + ((lc ^ (r0 & 7)) << 3);
    const unsigned short* pA1 = A  + (size_t)am1 * (KT - 128) + ((lc ^ (r1 & 7)) << 3);
    const unsigned short* pX0 = Xb + (size_t)am0 * 128        + ((lc ^ (r0 & 7)) << 3);
    const unsigned short* pX1 = Xb + (size_t)am1 * 128        + ((lc ^ (r1 & 7)) << 3);
    const unsigned short* pB0 = Bt + (size_t)r0 * KT          + ((lc ^ (r0 & 7)) << 3);
    const unsigned short* pB1 = Bt + (size_t)r1 * KT          + ((lc ^ (r1 & 7)) << 3);

    f32x4 acc[8] = {};

    auto issue = [&](int ko, int buf) {
        const unsigned short* a0 = (ko < NA) ? (pA0 + ko * 64) : (pX0 + (ko - NA) * 64);
        const unsigned short* a1 = (ko < NA) ? (pA1 + ko * 64) : (pX1 + (ko - NA) * 64);
        gld_lds16(a0,           &Asw[buf][(wave * 16 + 0) * 64]);
        gld_lds16(a1,           &Asw[buf][(wave * 16 + 8) * 64]);
        gld_lds16(pB0 + ko * 64, &Bsw[buf][(wave * 16 + 0) * 64]);
        gld_lds16(pB1 + ko * 64, &Bsw[buf][(wave * 16 + 8) * 64]);
    };
    auto mfma_phase = [&](int buf) {
#pragma unroll
        for (int ks = 0; ks < 2; ++ks) {          // two 16x16x32 K-slices
            short8 af[2], bf[4];
#pragma unroll
            for (int mi = 0; mi < 2; ++mi) {
                const int r = wm * 32 + mi * 16 + ln;
                af[mi] = *(const short8*)&Asw[buf][r * 64 + ((((ks << 2) + quad) ^ (r & 7)) << 3)];
            }
#pragma unroll
            for (int ci = 0; ci < 4; ++ci) {
                const int r = wn * 64 + ci * 16 + ln;
                bf[ci] = *(const short8*)&Bsw[buf][r * 64 + ((((ks << 2) + quad) ^ (r & 7)) << 3)];
            }
#pragma unroll
            for (int mi = 0; mi < 2; ++mi)
#pragma unroll
                for (int ci = 0; ci < 4; ++ci)
                    acc[mi * 4 + ci] = __builtin_amdgcn_mfma_f32_16x16x32_bf16(
                        af[mi], bf[ci], acc[mi * 4 + ci], 0, 0, 0);
        }
    };

    issue(0, 0);
    __syncthreads();                       // vmcnt(0) drain: tile0 in LDS

    int cur = 0;
#pragma unroll
    for (int ko = 0; ko < NI; ++ko) {
        if (ko + 1 < NI) issue(ko + 1, cur ^ 1);  // direct-to-LDS, other buffer
        __builtin_amdgcn_sched_barrier(0);        // keep issues above MFMA phase
        mfma_phase(cur);
        __syncthreads();                          // drains vmcnt -> buf^1 ready
        cur ^= 1;
    }

#pragma unroll
    for (int mi = 0; mi < 2; ++mi)
#pragma unroll
        for (int ci = 0; ci < 4; ++ci)
#pragma unroll
            for (int rg = 0; rg < 4; ++rg) {
                const int row = m0 + wm * 32 + mi * 16 + quad * 4 + rg;
                if (row < M)
                    out[(size_t)row * 128 + wn * 64 + ci * 16 + ln] = acc[mi * 4 + ci][rg];
            }
}

// Generic-K fallback (runtime loop bound), slow but correct
__global__ __launch_bounds__(256) void gemm_kernel_rt(
    const unsigned short* __restrict__ A, const unsigned short* __restrict__ Xb,
    const unsigned short* __restrict__ Bt, float* __restrict__ out,
    int M, int ktot)
{
    const int tid = threadIdx.x;
    const int wave = tid >> 6;
    const int lane = tid & 63;
    const int ln = lane & 15, quad = lane >> 4;
    const int m0 = blockIdx.x * 64 + wave * 16;
    int m = m0 + ln; if (m >= M) m = M - 1;
    const unsigned short* Arow = A + (size_t)m * (ktot - 128) + quad * 8;
    const unsigned short* Xrow = Xb + (size_t)m * 128 + quad * 8;
    const unsigned short* Bbase = Bt + (size_t)ln * ktot + quad * 8;

    f32x4 acc[8] = {};
    for (int kb = 0; kb < (ktot >> 5); ++kb) {
        const int k0 = kb << 5;
        const unsigned short* asrc = (k0 < ktot - 128) ? (Arow + k0) : (Xrow + (k0 - (ktot - 128)));
        const short8 a = *(const short8*)asrc;
#pragma unroll
        for (int c = 0; c < 8; ++c) {
            const short8 b = *(const short8*)(Bbase + (size_t)c * 16 * ktot + k0);
            acc[c] = __builtin_amdgcn_mfma_f32_16x16x32_bf16(a, b, acc[c], 0, 0, 0);
        }
    }
#pragma unroll
    for (int c = 0; c < 8; ++c) {
#pragma unroll
        for (int rg = 0; rg < 4; ++rg) {
            const int row = m0 + quad * 4 + rg;
            if (row < M) out[(size_t)row * 128 + c * 16 + ln] = acc[c][rg];
        }
    }
}

// ---------------------------------------------------------------------------
extern "C" void kernel_launch(void* const* d_in, const int* in_sizes, int n_in,
                              void* d_out, int out_size, void* d_ws, size_t ws_size,
                              hipStream_t stream) {
    const float* X        = (const float*)d_in[0];
    const float* W        = (const float*)d_in[1];
    const float* W0       = (const float*)d_in[2];
    const float* inv_norm = (const float*)d_in[3];
    const int*   esrc     = (const int*)d_in[4];
    const int*   edst     = (const int*)d_in[5];
    const int*   erel     = (const int*)d_in[6];
    float* out = (float*)d_out;

    const int N  = in_sizes[0] / 128;     // 50000
    const int E  = in_sizes[4];           // 800000
    const int R  = in_sizes[3] / N;       // 8
    const int KB = N * 8;                 // 400000 bins (dst*8+rel)
    const int ktot = (R + 1) * 128;       // 1152
    const int C  = (N + 255) >> 8;        // 196 coarse buckets (dst>>8)

    char* ws = (char*)d_ws;
    size_t off = 0;
    auto alloc = [&](size_t bytes) -> char* {
        char* p = ws + off; off = (off + bytes + 255) & ~(size_t)255; return p;
    };
    unsigned short* A         = (unsigned short*)alloc((size_t)N * R * 128 * 2); // 102.4 MB
    unsigned short* Xb        = (unsigned short*)alloc((size_t)N * 128 * 2);     // 12.8 MB
    unsigned short* Bt        = (unsigned short*)alloc((size_t)128 * ktot * 2);  // 0.3 MB
    int*            ccounts   = (int*)alloc((size_t)C * 4);
    int*            cstarts   = (int*)alloc((size_t)C * 4);
    int*            cursor    = (int*)alloc((size_t)C * 4);
    int*            starts    = (int*)alloc((size_t)KB * 4);                     // 1.6 MB
    unsigned*       staged    = (unsigned*)alloc((size_t)E * 4);                 // 3.2 MB
    unsigned*       sorted    = (unsigned*)alloc((size_t)E * 4);                 // 3.2 MB
    (void)ws_size;

    const int nEdgeBlocks = (E + 2047) / 2048;                    // 391
    const int nCastBlocks = (N * 32 + 128 * ktot + 255) / 256;    // ~6827

    hipMemsetAsync(ccounts, 0, (size_t)C * 4, stream);
    chist_kernel<<<nEdgeBlocks, 256, 0, stream>>>(edst, ccounts, E, C);
    cscan_kernel<<<1, 256, 0, stream>>>(ccounts, cstarts, cursor, C);
    partition_kernel<<<nEdgeBlocks, 256, 0, stream>>>(esrc, edst, erel, cursor, staged, E, C);
    binsortcast_kernel<<<C + nCastBlocks, 256, 0, stream>>>(
        staged, cstarts, starts, sorted, N, E, C, X, W, W0, Xb, Bt, R);
    aggregate_kernel<<<(N + 3) / 4, 256, 0, stream>>>(Xb, inv_norm, sorted, starts, A, N, E);
    if (ktot == 1152)
        gemm_kernel<1152><<<(N + 127) / 128, 512, 0, stream>>>(A, Xb, Bt, out, N);
    else
        gemm_kernel_rt<<<(N + 63) / 64, 256, 0, stream>>>(A, Xb, Bt, out, N, ktot);
}